// Round 2
// baseline (243.816 us; speedup 1.0000x reference)
//
#include <hip/hip_runtime.h>

// SlidingWindowAttention: B=1, S=4096, D=1024, H=16, d=64, WIN=512 (256 back / 255 fwd)
// Inputs/outputs are FP32 storage (values bf16-rounded by harness). Compute in
// bf16 MFMA with fp32 accumulation; intermediates (qkv, o) kept as bf16 in ws.
//
// Pipeline:
//   1) gemm_bt_bias<float,false>: qkv = x @ Wqkv^T + bqkv  (4096x3072, K=1024) -> ws (bf16)
//   2) swa_fused:                 per (head, 64-query blk) flash attention     -> ws (bf16)
//   3) gemm_bt_bias<u16,true>:    out = o @ Wout^T + bout  (4096x1024, K=1024) -> d_out (fp32)

typedef __bf16 bf16x8 __attribute__((ext_vector_type(8)));
typedef float f32x4 __attribute__((ext_vector_type(4)));
typedef unsigned short u16;
typedef unsigned int u32;

__device__ __forceinline__ float b2f(u16 v) {
  union { u32 u; float f; } x; x.u = ((u32)v) << 16; return x.f;
}
// round-to-nearest-even f32 -> bf16 bits
__device__ __forceinline__ u16 f2b(float f) {
  union { float f; u32 u; } x; x.f = f;
  u32 r = x.u + 0x7fffu + ((x.u >> 16) & 1u);
  return (u16)(r >> 16);
}

union U8x16 { int4 v; u16 u[8]; };

// stage 8 contiguous elements from global into LDS as bf16
template<typename T>
__device__ __forceinline__ void stage8(const T* __restrict__ g, u16* __restrict__ s) {
  if constexpr (sizeof(T) == 4) {   // fp32 source: two float4 loads, RNE to bf16
    const float4 a = *(const float4*)(g);
    const float4 b = *(const float4*)(g + 4);
    U8x16 t;
    t.u[0] = f2b(a.x); t.u[1] = f2b(a.y); t.u[2] = f2b(a.z); t.u[3] = f2b(a.w);
    t.u[4] = f2b(b.x); t.u[5] = f2b(b.y); t.u[6] = f2b(b.z); t.u[7] = f2b(b.w);
    *(int4*)s = t.v;
  } else {                          // bf16 source: one 16B copy
    *(int4*)s = *(const int4*)g;
  }
}

// ---------------------------------------------------------------------------
// GEMM: C[M,N] = A[M,K] @ B[N,K]^T + bias[N]; fp32 acc. A dtype = TA (fp32 or
// bf16-u16); B/bias fp32; C written as fp32 (OUT_F32) or bf16 ws (!OUT_F32).
// 128x128 tile per 256-thread block (2x2 waves, each 64x64 via 4x4 MFMA
// 16x16x32 tiles). BK=32. LDS rows padded to 40 bf16 (2-way alias = free).
// M,N,K multiples of 128/128/32 here -> no bounds checks.
// ---------------------------------------------------------------------------
#define LDT 40

template<typename TA, bool OUT_F32>
__global__ __launch_bounds__(256, 2) void gemm_bt_bias(
    const TA* __restrict__ A, const float* __restrict__ B,
    const float* __restrict__ bias, void* __restrict__ Cv,
    int M, int N, int K)
{
  __shared__ u16 As[128 * LDT];
  __shared__ u16 Bs[128 * LDT];

  const int tid  = threadIdx.x;
  const int lane = tid & 63;
  const int wave = tid >> 6;
  const int quad = lane >> 4;
  const int c16  = lane & 15;
  const int wr   = wave >> 1;
  const int wc   = wave & 1;
  const long m0 = (long)blockIdx.y * 128;
  const long n0 = (long)blockIdx.x * 128;

  // staging: 128 rows x 32 cols = 512 chunks of 8 elems; 2 chunks/thread/matrix
  const int sr0 = tid >> 2;        // rows 0..63
  const int sr1 = sr0 + 64;        // rows 64..127
  const int sc  = (tid & 3) * 8;   // 0,8,16,24

  f32x4 acc[4][4];
#pragma unroll
  for (int i = 0; i < 4; ++i)
#pragma unroll
    for (int j = 0; j < 4; ++j)
      acc[i][j] = f32x4{0.f, 0.f, 0.f, 0.f};

  for (int k0 = 0; k0 < K; k0 += 32) {
    __syncthreads();
    stage8(&A[(m0 + sr0) * K + k0 + sc], &As[sr0 * LDT + sc]);
    stage8(&A[(m0 + sr1) * K + k0 + sc], &As[sr1 * LDT + sc]);
    stage8(&B[(n0 + sr0) * K + k0 + sc], &Bs[sr0 * LDT + sc]);
    stage8(&B[(n0 + sr1) * K + k0 + sc], &Bs[sr1 * LDT + sc]);
    __syncthreads();

    bf16x8 af[4], bfr[4];
#pragma unroll
    for (int i = 0; i < 4; ++i)
      af[i] = *(const bf16x8*)(&As[(wr * 64 + i * 16 + c16) * LDT + quad * 8]);
#pragma unroll
    for (int j = 0; j < 4; ++j)
      bfr[j] = *(const bf16x8*)(&Bs[(wc * 64 + j * 16 + c16) * LDT + quad * 8]);
#pragma unroll
    for (int i = 0; i < 4; ++i)
#pragma unroll
      for (int j = 0; j < 4; ++j)
        acc[i][j] = __builtin_amdgcn_mfma_f32_16x16x32_bf16(af[i], bfr[j], acc[i][j], 0, 0, 0);
  }

  // epilogue: C/D layout col=lane&15, row=quad*4+reg
#pragma unroll
  for (int i = 0; i < 4; ++i) {
    const long row0 = m0 + wr * 64 + i * 16 + quad * 4;
#pragma unroll
    for (int j = 0; j < 4; ++j) {
      const long col = n0 + wc * 64 + j * 16 + c16;
      const float bv = bias[col];
#pragma unroll
      for (int r = 0; r < 4; ++r) {
        const float val = acc[i][j][r] + bv;
        if constexpr (OUT_F32) ((float*)Cv)[(row0 + r) * N + col] = val;
        else                   ((u16*)Cv)[(row0 + r) * N + col]   = f2b(val);
      }
    }
  }
}

// ---------------------------------------------------------------------------
// Sliding-window flash attention (bf16 qkv ws in, bf16 o ws out).
// Grid: (S/64 query blocks, H heads). Block: 256 threads = 4 waves.
// Wave w owns queries [qb0+16w, qb0+16w+16). Keys streamed in 9 tiles of 64
// covering [qb0-256, qb0+320); out-of-sequence keys zero-filled (score 0,
// v=0 -> matches reference zero-padding, which IS included in softmax).
// Band: key kp valid for query qp iff qp-256 <= kp <= qp+255.
// V transposed on store into LDS so PV B-fragments are contiguous b128 reads.
// P round-trips through LDS (C-layout -> A-layout), per m120 pattern.
// ---------------------------------------------------------------------------
#define LDK 72

__global__ __launch_bounds__(256, 2) void swa_fused(
    const u16* __restrict__ qkv, u16* __restrict__ o)
{
  __shared__ u16 Ks[64 * LDK];         // K tile, (key, d) row-major
  __shared__ u16 VTs[64 * LDK];        // V tile transposed, (d, key)
  __shared__ u16 Ps[4 * 16 * LDK];     // per-wave P (16 q x 64 keys)

  const int tid  = threadIdx.x;
  const int lane = tid & 63;
  const int wave = tid >> 6;
  const int quad = lane >> 4;
  const int c16  = lane & 15;
  const int h    = blockIdx.y;
  const int qb0  = blockIdx.x * 64;

  const int S  = 4096;
  const long D3 = 3072;

  // Q fragments (A-layout): rows qb0+16*wave+c16, dims quad*8.. (+32)
  const long qrow = qb0 + wave * 16 + c16;
  const bf16x8 aq0 = *(const bf16x8*)(&qkv[qrow * D3 + h * 64 + quad * 8]);
  const bf16x8 aq1 = *(const bf16x8*)(&qkv[qrow * D3 + h * 64 + 32 + quad * 8]);

  f32x4 acc[4];
#pragma unroll
  for (int dt = 0; dt < 4; ++dt) acc[dt] = f32x4{0.f, 0.f, 0.f, 0.f};
  float m_i[4], l_i[4];
#pragma unroll
  for (int r = 0; r < 4; ++r) { m_i[r] = -INFINITY; l_i[r] = 0.f; }

  const int kb0 = qb0 - 256;
  const int qp  = qb0 + wave * 16 + quad * 4;  // this lane's query row base

  for (int it = 0; it < 9; ++it) {
    const int kt0 = kb0 + it * 64;
    __syncthreads();  // protect prior iteration's LDS reads
    // stage K (row-major) and V (transposed) for 64 keys
    for (int cc = tid; cc < 512; cc += 256) {
      const int krow = cc >> 3;
      const int c8   = (cc & 7) * 8;
      const int kp   = kt0 + krow;
      int4 kv = {0, 0, 0, 0}, vv = {0, 0, 0, 0};
      if (kp >= 0 && kp < S) {
        kv = *(const int4*)(&qkv[(long)kp * D3 + 1024 + h * 64 + c8]);
        vv = *(const int4*)(&qkv[(long)kp * D3 + 2048 + h * 64 + c8]);
      }
      *(int4*)(&Ks[krow * LDK + c8]) = kv;
      U8x16 tv; tv.v = vv;
#pragma unroll
      for (int j = 0; j < 8; ++j)
        VTs[(c8 + j) * LDK + krow] = tv.u[j];
    }
    __syncthreads();

    // S = Q K^T for 4 key col-tiles of 16
    f32x4 s[4];
#pragma unroll
    for (int t = 0; t < 4; ++t) {
      const bf16x8 bk0 = *(const bf16x8*)(&Ks[(t * 16 + c16) * LDK + quad * 8]);
      const bf16x8 bk1 = *(const bf16x8*)(&Ks[(t * 16 + c16) * LDK + 32 + quad * 8]);
      f32x4 c = f32x4{0.f, 0.f, 0.f, 0.f};
      c = __builtin_amdgcn_mfma_f32_16x16x32_bf16(aq0, bk0, c, 0, 0, 0);
      c = __builtin_amdgcn_mfma_f32_16x16x32_bf16(aq1, bk1, c, 0, 0, 0);
      s[t] = c;
    }

    // scale + band mask + per-tile row max
    float tmax[4] = {-INFINITY, -INFINITY, -INFINITY, -INFINITY};
#pragma unroll
    for (int t = 0; t < 4; ++t) {
      const int kp_col = kt0 + t * 16 + c16;
#pragma unroll
      for (int r = 0; r < 4; ++r) {
        const int qpr = qp + r;
        const bool ok = (kp_col >= qpr - 256) && (kp_col <= qpr + 255);
        const float v = ok ? s[t][r] * 0.125f : -INFINITY;
        s[t][r] = v;
        tmax[r] = fmaxf(tmax[r], v);
      }
    }
    // row reduce across the 16 lanes of each quad (a score row lives in one quad)
#pragma unroll
    for (int off = 1; off < 16; off <<= 1)
#pragma unroll
      for (int r = 0; r < 4; ++r)
        tmax[r] = fmaxf(tmax[r], __shfl_xor(tmax[r], off, 64));

    // online softmax update (tile 0 always has >=1 in-band key per row ->
    // m_i finite from it=0; exp(-inf - finite) = 0)
    float alpha[4];
#pragma unroll
    for (int r = 0; r < 4; ++r) {
      const float nm = fmaxf(m_i[r], tmax[r]);
      alpha[r] = __expf(m_i[r] - nm);
      m_i[r]   = nm;
    }

    float rsum[4] = {0.f, 0.f, 0.f, 0.f};
    u16* Pw = &Ps[wave * 16 * LDK];
#pragma unroll
    for (int t = 0; t < 4; ++t)
#pragma unroll
      for (int r = 0; r < 4; ++r) {
        const float p = __expf(s[t][r] - m_i[r]);
        rsum[r] += p;
        Pw[(quad * 4 + r) * LDK + t * 16 + c16] = f2b(p);  // C-layout -> LDS
      }
#pragma unroll
    for (int off = 1; off < 16; off <<= 1)
#pragma unroll
      for (int r = 0; r < 4; ++r)
        rsum[r] += __shfl_xor(rsum[r], off, 64);
#pragma unroll
    for (int r = 0; r < 4; ++r)
      l_i[r] = l_i[r] * alpha[r] + rsum[r];
#pragma unroll
    for (int dt = 0; dt < 4; ++dt)
#pragma unroll
      for (int r = 0; r < 4; ++r)
        acc[dt][r] *= alpha[r];

    __syncthreads();  // P writes visible before A-layout reads

    // O += P V : A = P (16x64) in A-layout, B = V^T tiles (b128 reads)
    const bf16x8 ap0 = *(const bf16x8*)(&Pw[c16 * LDK + quad * 8]);
    const bf16x8 ap1 = *(const bf16x8*)(&Pw[c16 * LDK + 32 + quad * 8]);
#pragma unroll
    for (int dt = 0; dt < 4; ++dt) {
      const bf16x8 bv0 = *(const bf16x8*)(&VTs[(dt * 16 + c16) * LDK + quad * 8]);
      const bf16x8 bv1 = *(const bf16x8*)(&VTs[(dt * 16 + c16) * LDK + 32 + quad * 8]);
      acc[dt] = __builtin_amdgcn_mfma_f32_16x16x32_bf16(ap0, bv0, acc[dt], 0, 0, 0);
      acc[dt] = __builtin_amdgcn_mfma_f32_16x16x32_bf16(ap1, bv1, acc[dt], 0, 0, 0);
    }
  }

  // write o in (S, H, d) layout == (S, D) matrix for the output projection
#pragma unroll
  for (int dt = 0; dt < 4; ++dt)
#pragma unroll
    for (int r = 0; r < 4; ++r)
      o[(long)(qp + r) * 1024 + h * 64 + dt * 16 + c16] = f2b(acc[dt][r] / l_i[r]);
}

// ---------------------------------------------------------------------------
extern "C" void kernel_launch(void* const* d_in, const int* in_sizes, int n_in,
                              void* d_out, int out_size, void* d_ws, size_t ws_size,
                              hipStream_t stream)
{
  const float* x    = (const float*)d_in[0];   // (4096, 1024) fp32
  const float* Wqkv = (const float*)d_in[1];   // (3072, 1024) fp32
  const float* bqkv = (const float*)d_in[2];   // (3072,) fp32
  const float* Wout = (const float*)d_in[3];   // (1024, 1024) fp32
  const float* bout = (const float*)d_in[4];   // (1024,) fp32
  float* out = (float*)d_out;                  // (4096, 1024) fp32

  // workspace: qkv (4096x3072 bf16 = 25.2 MB) + o (4096x1024 bf16 = 8.4 MB)
  u16* qkv = (u16*)d_ws;
  u16* o   = qkv + (size_t)4096 * 3072;

  gemm_bt_bias<float, false><<<dim3(3072 / 128, 4096 / 128), 256, 0, stream>>>(
      x, Wqkv, bqkv, (void*)qkv, 4096, 3072, 1024);
  swa_fused<<<dim3(4096 / 64, 16), 256, 0, stream>>>(qkv, o);
  gemm_bt_bias<u16, true><<<dim3(1024 / 128, 4096 / 128), 256, 0, stream>>>(
      o, Wout, bout, (void*)out, 4096, 1024, 1024);
}

// Round 3
// 197.930 us; speedup vs baseline: 1.2318x; 1.2318x over previous
//
#include <hip/hip_runtime.h>

// SlidingWindowAttention: B=1, S=4096, D=1024, H=16, d=64, WIN=512 (256 back / 255 fwd)
// Inputs/outputs FP32 storage (values bf16-rounded by harness).
//
// Pipeline:
//   0) cvt_f32_bf16 x3:  x, Wqkv, Wout -> bf16 copies in ws (~8 us, HBM-bound)
//   1) gemm_bt_bias<false>: qkv = xb @ Wqkvb^T + bqkv  (4096x3072, K=1024) -> ws bf16
//   2) swa_fused:           per (head, 64-query blk) flash attention       -> ws bf16
//   3) gemm_bt_bias<true>:  out = o @ Woutb^T + bout   (4096x1024, K=1024) -> d_out fp32
//
// GEMM is m97-style: 128x128 tile, BK=32, global_load_lds 16B staging (async
// DMA, no VGPR round-trip), XOR-swizzled chunk layout so both the DMA writes
// and the ds_read_b128 fragment reads are bank-conflict-free (2-way max).

typedef __bf16 bf16x8 __attribute__((ext_vector_type(8)));
typedef float f32x4 __attribute__((ext_vector_type(4)));
typedef unsigned short u16;
typedef unsigned int u32;

__device__ __forceinline__ u16 f2b(float f) {   // RNE f32 -> bf16 bits
  union { float f; u32 u; } x; x.f = f;
  u32 r = x.u + 0x7fffu + ((x.u >> 16) & 1u);
  return (u16)(r >> 16);
}

union U8x16 { int4 v; u16 u[8]; };

// async 16B global -> LDS (dest = wave-uniform base + lane*16, HW-generated)
__device__ __forceinline__ void gll16(const u16* g, u16* l) {
  __builtin_amdgcn_global_load_lds(
      (const __attribute__((address_space(1))) u16*)g,
      (__attribute__((address_space(3))) u16*)l,
      16, 0, 0);
}

// ---------------------------------------------------------------------------
// fp32 -> bf16 conversion (8 elems/thread)
// ---------------------------------------------------------------------------
__global__ void cvt_f32_bf16(const float* __restrict__ in, u16* __restrict__ out, int n8)
{
  const int i = blockIdx.x * blockDim.x + threadIdx.x;
  if (i >= n8) return;
  const float4 a = ((const float4*)in)[i * 2];
  const float4 b = ((const float4*)in)[i * 2 + 1];
  U8x16 t;
  t.u[0] = f2b(a.x); t.u[1] = f2b(a.y); t.u[2] = f2b(a.z); t.u[3] = f2b(a.w);
  t.u[4] = f2b(b.x); t.u[5] = f2b(b.y); t.u[6] = f2b(b.z); t.u[7] = f2b(b.w);
  ((int4*)out)[i] = t.v;
}

// ---------------------------------------------------------------------------
// GEMM: C[M,N] = A[M,K] @ B[N,K]^T + bias[N]; A,B bf16, fp32 acc.
// 128x128 tile / 256-thread block (2x2 waves, each 64x64 via 4x4 MFMA
// 16x16x32 tiles). BK=32, unpadded LDS (global_load_lds requirement).
//
// Swizzle: a tile row is 4 chunks of 8 bf16 (16B). Storage slot for (row,
// chunk) is chunk' = chunk ^ ((row>>1)&3). DMA lane i (covering 16 rows x 4
// chunks) therefore LOADS global chunk (i&3)^((i>>3)&3) into its fixed slot
// i&3; fragment reads use slot quad^((c16>>1)&3). Bank groups per quad cover
// all 8 groups exactly twice -> conflict-free.
// M,N,K multiples of 128/128/32 here -> no bounds checks.
// ---------------------------------------------------------------------------
template<bool OUT_F32>
__global__ __launch_bounds__(256, 2) void gemm_bt_bias(
    const u16* __restrict__ A, const u16* __restrict__ B,
    const float* __restrict__ bias, void* __restrict__ Cv,
    int M, int N, int K)
{
  __shared__ u16 As[128 * 32];   // 8 KB, unpadded
  __shared__ u16 Bs[128 * 32];

  const int tid  = threadIdx.x;
  const int lane = tid & 63;
  const int wave = tid >> 6;
  const int quad = lane >> 4;
  const int c16  = lane & 15;
  const int wr   = wave >> 1;
  const int wc   = wave & 1;
  const long m0 = (long)blockIdx.y * 128;
  const long n0 = (long)blockIdx.x * 128;

  // --- staging addresses: wave stages rows [wave*32, wave*32+32) of each tile
  //     via 2 DMA instrs per matrix (16 rows each: lane i -> row base+(i>>2))
  const int srow   = wave * 32 + (lane >> 2);
  const int schunk = (lane & 3) ^ ((lane >> 3) & 3);   // swizzled global chunk
  const u16* gA0 = &A[(m0 + srow) * K + schunk * 8];
  const u16* gA1 = &A[(m0 + srow + 16) * K + schunk * 8];
  const u16* gB0 = &B[(n0 + srow) * K + schunk * 8];
  const u16* gB1 = &B[(n0 + srow + 16) * K + schunk * 8];
  u16* const lA0 = &As[(wave * 32) * 32];
  u16* const lA1 = &As[(wave * 32 + 16) * 32];
  u16* const lB0 = &Bs[(wave * 32) * 32];
  u16* const lB1 = &Bs[(wave * 32 + 16) * 32];

  // --- fragment LDS pointers (K-loop invariant)
  const int cs = (quad ^ ((c16 >> 1) & 3)) * 8;        // swizzled slot
  const u16* pa[4]; const u16* pb[4];
#pragma unroll
  for (int i = 0; i < 4; ++i) {
    pa[i] = &As[(wr * 64 + i * 16 + c16) * 32 + cs];
    pb[i] = &Bs[(wc * 64 + i * 16 + c16) * 32 + cs];
  }

  f32x4 acc[4][4];
#pragma unroll
  for (int i = 0; i < 4; ++i)
#pragma unroll
    for (int j = 0; j < 4; ++j)
      acc[i][j] = f32x4{0.f, 0.f, 0.f, 0.f};

  for (int k0 = 0; k0 < K; k0 += 32) {
    __syncthreads();               // prior iteration's ds_reads done
    gll16(gA0, lA0); gll16(gA1, lA1);
    gll16(gB0, lB0); gll16(gB1, lB1);
    gA0 += 32; gA1 += 32; gB0 += 32; gB1 += 32;
    __syncthreads();               // DMA drained (compiler emits vmcnt(0))

    bf16x8 af[4], bfr[4];
#pragma unroll
    for (int i = 0; i < 4; ++i) af[i]  = *(const bf16x8*)pa[i];
#pragma unroll
    for (int j = 0; j < 4; ++j) bfr[j] = *(const bf16x8*)pb[j];
#pragma unroll
    for (int i = 0; i < 4; ++i)
#pragma unroll
      for (int j = 0; j < 4; ++j)
        acc[i][j] = __builtin_amdgcn_mfma_f32_16x16x32_bf16(af[i], bfr[j], acc[i][j], 0, 0, 0);
  }

  // epilogue: C/D layout col=lane&15, row=quad*4+reg
#pragma unroll
  for (int i = 0; i < 4; ++i) {
    const long row0 = m0 + wr * 64 + i * 16 + quad * 4;
#pragma unroll
    for (int j = 0; j < 4; ++j) {
      const long col = n0 + wc * 64 + j * 16 + c16;
      const float bv = bias[col];
#pragma unroll
      for (int r = 0; r < 4; ++r) {
        const float val = acc[i][j][r] + bv;
        if constexpr (OUT_F32) ((float*)Cv)[(row0 + r) * N + col] = val;
        else                   ((u16*)Cv)[(row0 + r) * N + col]   = f2b(val);
      }
    }
  }
}

// ---------------------------------------------------------------------------
// Sliding-window flash attention (bf16 qkv ws in, bf16 o ws out).
// Grid: (S/64 query blocks, H heads). Block: 256 threads = 4 waves.
// Wave w owns queries [qb0+16w, qb0+16w+16). Keys streamed in 9 tiles of 64
// covering [qb0-256, qb0+320); out-of-sequence keys zero-filled (score 0,
// v=0 -> matches reference zero-padding, which IS included in softmax).
// Band: key kp valid for query qp iff qp-256 <= kp <= qp+255.
// ---------------------------------------------------------------------------
#define LDK 72

__global__ __launch_bounds__(256, 2) void swa_fused(
    const u16* __restrict__ qkv, u16* __restrict__ o)
{
  __shared__ u16 Ks[64 * LDK];         // K tile, (key, d) row-major
  __shared__ u16 VTs[64 * LDK];        // V tile transposed, (d, key)
  __shared__ u16 Ps[4 * 16 * LDK];     // per-wave P (16 q x 64 keys)

  const int tid  = threadIdx.x;
  const int lane = tid & 63;
  const int wave = tid >> 6;
  const int quad = lane >> 4;
  const int c16  = lane & 15;
  const int h    = blockIdx.y;
  const int qb0  = blockIdx.x * 64;

  const int S  = 4096;
  const long D3 = 3072;

  const long qrow = qb0 + wave * 16 + c16;
  const bf16x8 aq0 = *(const bf16x8*)(&qkv[qrow * D3 + h * 64 + quad * 8]);
  const bf16x8 aq1 = *(const bf16x8*)(&qkv[qrow * D3 + h * 64 + 32 + quad * 8]);

  f32x4 acc[4];
#pragma unroll
  for (int dt = 0; dt < 4; ++dt) acc[dt] = f32x4{0.f, 0.f, 0.f, 0.f};
  float m_i[4], l_i[4];
#pragma unroll
  for (int r = 0; r < 4; ++r) { m_i[r] = -INFINITY; l_i[r] = 0.f; }

  const int kb0 = qb0 - 256;
  const int qp  = qb0 + wave * 16 + quad * 4;

  for (int it = 0; it < 9; ++it) {
    const int kt0 = kb0 + it * 64;
    __syncthreads();
    for (int cc = tid; cc < 512; cc += 256) {
      const int krow = cc >> 3;
      const int c8   = (cc & 7) * 8;
      const int kp   = kt0 + krow;
      int4 kv = {0, 0, 0, 0}, vv = {0, 0, 0, 0};
      if (kp >= 0 && kp < S) {
        kv = *(const int4*)(&qkv[(long)kp * D3 + 1024 + h * 64 + c8]);
        vv = *(const int4*)(&qkv[(long)kp * D3 + 2048 + h * 64 + c8]);
      }
      *(int4*)(&Ks[krow * LDK + c8]) = kv;
      U8x16 tv; tv.v = vv;
#pragma unroll
      for (int j = 0; j < 8; ++j)
        VTs[(c8 + j) * LDK + krow] = tv.u[j];
    }
    __syncthreads();

    f32x4 s[4];
#pragma unroll
    for (int t = 0; t < 4; ++t) {
      const bf16x8 bk0 = *(const bf16x8*)(&Ks[(t * 16 + c16) * LDK + quad * 8]);
      const bf16x8 bk1 = *(const bf16x8*)(&Ks[(t * 16 + c16) * LDK + 32 + quad * 8]);
      f32x4 c = f32x4{0.f, 0.f, 0.f, 0.f};
      c = __builtin_amdgcn_mfma_f32_16x16x32_bf16(aq0, bk0, c, 0, 0, 0);
      c = __builtin_amdgcn_mfma_f32_16x16x32_bf16(aq1, bk1, c, 0, 0, 0);
      s[t] = c;
    }

    float tmax[4] = {-INFINITY, -INFINITY, -INFINITY, -INFINITY};
#pragma unroll
    for (int t = 0; t < 4; ++t) {
      const int kp_col = kt0 + t * 16 + c16;
#pragma unroll
      for (int r = 0; r < 4; ++r) {
        const int qpr = qp + r;
        const bool ok = (kp_col >= qpr - 256) && (kp_col <= qpr + 255);
        const float v = ok ? s[t][r] * 0.125f : -INFINITY;
        s[t][r] = v;
        tmax[r] = fmaxf(tmax[r], v);
      }
    }
#pragma unroll
    for (int off = 1; off < 16; off <<= 1)
#pragma unroll
      for (int r = 0; r < 4; ++r)
        tmax[r] = fmaxf(tmax[r], __shfl_xor(tmax[r], off, 64));

    float alpha[4];
#pragma unroll
    for (int r = 0; r < 4; ++r) {
      const float nm = fmaxf(m_i[r], tmax[r]);
      alpha[r] = __expf(m_i[r] - nm);
      m_i[r]   = nm;
    }

    float rsum[4] = {0.f, 0.f, 0.f, 0.f};
    u16* Pw = &Ps[wave * 16 * LDK];
#pragma unroll
    for (int t = 0; t < 4; ++t)
#pragma unroll
      for (int r = 0; r < 4; ++r) {
        const float p = __expf(s[t][r] - m_i[r]);
        rsum[r] += p;
        Pw[(quad * 4 + r) * LDK + t * 16 + c16] = f2b(p);
      }
#pragma unroll
    for (int off = 1; off < 16; off <<= 1)
#pragma unroll
      for (int r = 0; r < 4; ++r)
        rsum[r] += __shfl_xor(rsum[r], off, 64);
#pragma unroll
    for (int r = 0; r < 4; ++r)
      l_i[r] = l_i[r] * alpha[r] + rsum[r];
#pragma unroll
    for (int dt = 0; dt < 4; ++dt)
#pragma unroll
      for (int r = 0; r < 4; ++r)
        acc[dt][r] *= alpha[r];

    __syncthreads();

    const bf16x8 ap0 = *(const bf16x8*)(&Pw[c16 * LDK + quad * 8]);
    const bf16x8 ap1 = *(const bf16x8*)(&Pw[c16 * LDK + 32 + quad * 8]);
#pragma unroll
    for (int dt = 0; dt < 4; ++dt) {
      const bf16x8 bv0 = *(const bf16x8*)(&VTs[(dt * 16 + c16) * LDK + quad * 8]);
      const bf16x8 bv1 = *(const bf16x8*)(&VTs[(dt * 16 + c16) * LDK + 32 + quad * 8]);
      acc[dt] = __builtin_amdgcn_mfma_f32_16x16x32_bf16(ap0, bv0, acc[dt], 0, 0, 0);
      acc[dt] = __builtin_amdgcn_mfma_f32_16x16x32_bf16(ap1, bv1, acc[dt], 0, 0, 0);
    }
  }

#pragma unroll
  for (int dt = 0; dt < 4; ++dt)
#pragma unroll
    for (int r = 0; r < 4; ++r)
      o[(long)(qp + r) * 1024 + h * 64 + dt * 16 + c16] = f2b(acc[dt][r] / l_i[r]);
}

// ---------------------------------------------------------------------------
extern "C" void kernel_launch(void* const* d_in, const int* in_sizes, int n_in,
                              void* d_out, int out_size, void* d_ws, size_t ws_size,
                              hipStream_t stream)
{
  const float* x    = (const float*)d_in[0];   // (4096, 1024) fp32
  const float* Wqkv = (const float*)d_in[1];   // (3072, 1024) fp32
  const float* bqkv = (const float*)d_in[2];   // (3072,) fp32
  const float* Wout = (const float*)d_in[3];   // (1024, 1024) fp32
  const float* bout = (const float*)d_in[4];   // (1024,) fp32
  float* out = (float*)d_out;                  // (4096, 1024) fp32

  // ws layout (bf16): qkv 25.2MB | xb 8.4MB (reused as o after GEMM1) |
  //                   Wqkvb 6.3MB | Woutb 2.1MB   -> 42MB total
  u16* qkv   = (u16*)d_ws;
  u16* xb    = qkv + (size_t)4096 * 3072;
  u16* o     = xb;                              // alias: xb dead after GEMM1
  u16* wqkvb = xb + (size_t)4096 * 1024;
  u16* woutb = wqkvb + (size_t)3072 * 1024;

  cvt_f32_bf16<<<(4096 * 1024 / 8 + 255) / 256, 256, 0, stream>>>(x, xb, 4096 * 1024 / 8);
  cvt_f32_bf16<<<(3072 * 1024 / 8 + 255) / 256, 256, 0, stream>>>(Wqkv, wqkvb, 3072 * 1024 / 8);
  cvt_f32_bf16<<<(1024 * 1024 / 8 + 255) / 256, 256, 0, stream>>>(Wout, woutb, 1024 * 1024 / 8);

  gemm_bt_bias<false><<<dim3(3072 / 128, 4096 / 128), 256, 0, stream>>>(
      xb, wqkvb, bqkv, (void*)qkv, 4096, 3072, 1024);
  swa_fused<<<dim3(4096 / 64, 16), 256, 0, stream>>>(qkv, o);
  gemm_bt_bias<true><<<dim3(1024 / 128, 4096 / 128), 256, 0, stream>>>(
      o, woutb, bout, (void*)out, 4096, 1024, 1024);
}

// Round 4
// 176.861 us; speedup vs baseline: 1.3786x; 1.1191x over previous
//
#include <hip/hip_runtime.h>

// SlidingWindowAttention: B=1, S=4096, D=1024, H=16, d=64, WIN=512 (256 back / 255 fwd)
// Inputs/outputs FP32 storage (values bf16-rounded by harness).
//
// Pipeline:
//   0) cvt_f32_bf16 x3 : x, Wqkv, Wout -> bf16 (ws)
//   1) gemm_qkv        : qkv GEMM, epilogue scatters Q->Qb(S,D), K->Kp padded
//                        (h,key+256,d), V->Vb(S,D)
//   2) repack_v        : Vb -> VTp padded (h,d,key+256); zeroes Kp/VTp pads
//   3) swa_fused       : 128 queries/block, 10 key tiles, pure gll16 staging,
//                        fixed-max softmax -> o (aliases Vb)
//   4) gemm_out        : out = o @ Wout^T + bout -> fp32

typedef __bf16 bf16x8 __attribute__((ext_vector_type(8)));
typedef float f32x4 __attribute__((ext_vector_type(4)));
typedef unsigned short u16;
typedef unsigned int u32;

#define MFMA16(a, b, c) __builtin_amdgcn_mfma_f32_16x16x32_bf16(a, b, c, 0, 0, 0)

__device__ __forceinline__ u16 f2b(float f) {   // RNE f32 -> bf16 bits
  union { float f; u32 u; } x; x.f = f;
  u32 r = x.u + 0x7fffu + ((x.u >> 16) & 1u);
  return (u16)(r >> 16);
}

union U8x16 { int4 v; u16 u[8]; };

// async 16B global -> LDS (dest = wave-uniform base + lane*16, HW-generated)
__device__ __forceinline__ void gll16(const u16* g, u16* l) {
  __builtin_amdgcn_global_load_lds(
      (const __attribute__((address_space(1))) u16*)g,
      (__attribute__((address_space(3))) u16*)l, 16, 0, 0);
}

// ---------------------------------------------------------------------------
__global__ void cvt_f32_bf16(const float* __restrict__ in, u16* __restrict__ out, int n8)
{
  const int i = blockIdx.x * blockDim.x + threadIdx.x;
  if (i >= n8) return;
  const float4 a = ((const float4*)in)[i * 2];
  const float4 b = ((const float4*)in)[i * 2 + 1];
  U8x16 t;
  t.u[0] = f2b(a.x); t.u[1] = f2b(a.y); t.u[2] = f2b(a.z); t.u[3] = f2b(a.w);
  t.u[4] = f2b(b.x); t.u[5] = f2b(b.y); t.u[6] = f2b(b.z); t.u[7] = f2b(b.w);
  ((int4*)out)[i] = t.v;
}

// ---------------------------------------------------------------------------
// QKV GEMM: 128x128 tile, BK=32, gll16 staging w/ XOR chunk swizzle (as R3).
// Epilogue scatters by column region: Q (n<1024) -> Qb row-major; K -> Kp
// (h, key+256, d); V -> Vb row-major. All branches block-uniform.
// ---------------------------------------------------------------------------
__global__ __launch_bounds__(256, 2) void gemm_qkv(
    const u16* __restrict__ A, const u16* __restrict__ B,
    const float* __restrict__ bias,
    u16* __restrict__ Qb, u16* __restrict__ Kp, u16* __restrict__ Vb)
{
  __shared__ u16 As[128 * 32];
  __shared__ u16 Bs[128 * 32];

  const int K = 1024, N = 3072;
  const int tid  = threadIdx.x;
  const int lane = tid & 63;
  const int wave = tid >> 6;
  const int quad = lane >> 4;
  const int c16  = lane & 15;
  const int wr   = wave >> 1;
  const int wc   = wave & 1;
  const long m0 = (long)blockIdx.y * 128;
  const long n0 = (long)blockIdx.x * 128;

  const int srow   = wave * 32 + (lane >> 2);
  const int schunk = (lane & 3) ^ ((lane >> 3) & 3);
  const u16* gA0 = &A[(m0 + srow) * K + schunk * 8];
  const u16* gA1 = &A[(m0 + srow + 16) * K + schunk * 8];
  const u16* gB0 = &B[(n0 + srow) * K + schunk * 8];
  const u16* gB1 = &B[(n0 + srow + 16) * K + schunk * 8];
  u16* const lA0 = &As[(wave * 32) * 32];
  u16* const lA1 = &As[(wave * 32 + 16) * 32];
  u16* const lB0 = &Bs[(wave * 32) * 32];
  u16* const lB1 = &Bs[(wave * 32 + 16) * 32];

  const int cs = (quad ^ ((c16 >> 1) & 3)) * 8;
  const u16* pa[4]; const u16* pb[4];
#pragma unroll
  for (int i = 0; i < 4; ++i) {
    pa[i] = &As[(wr * 64 + i * 16 + c16) * 32 + cs];
    pb[i] = &Bs[(wc * 64 + i * 16 + c16) * 32 + cs];
  }

  f32x4 acc[4][4];
#pragma unroll
  for (int i = 0; i < 4; ++i)
#pragma unroll
    for (int j = 0; j < 4; ++j)
      acc[i][j] = f32x4{0.f, 0.f, 0.f, 0.f};

  for (int k0 = 0; k0 < K; k0 += 32) {
    __syncthreads();
    gll16(gA0, lA0); gll16(gA1, lA1);
    gll16(gB0, lB0); gll16(gB1, lB1);
    gA0 += 32; gA1 += 32; gB0 += 32; gB1 += 32;
    __syncthreads();

    bf16x8 af[4], bfr[4];
#pragma unroll
    for (int i = 0; i < 4; ++i) af[i]  = *(const bf16x8*)pa[i];
#pragma unroll
    for (int j = 0; j < 4; ++j) bfr[j] = *(const bf16x8*)pb[j];
#pragma unroll
    for (int i = 0; i < 4; ++i)
#pragma unroll
      for (int j = 0; j < 4; ++j)
        acc[i][j] = MFMA16(af[i], bfr[j], acc[i][j]);
  }

  const int region = (int)(n0 >> 10);      // 0=Q, 1=K, 2=V (block-uniform)
#pragma unroll
  for (int i = 0; i < 4; ++i) {
    const long row0 = m0 + wr * 64 + i * 16 + quad * 4;
#pragma unroll
    for (int j = 0; j < 4; ++j) {
      const long col = n0 + wc * 64 + j * 16 + c16;
      const float bv = bias[col];
#pragma unroll
      for (int r = 0; r < 4; ++r) {
        const u16 v = f2b(acc[i][j][r] + bv);
        const long row = row0 + r;
        if (region == 0) {
          Qb[row * 1024 + col] = v;
        } else if (region == 1) {
          const int n1 = (int)(col - 1024);
          const int h = n1 >> 6, d = n1 & 63;
          Kp[((long)h * 4608 + row + 256) * 64 + d] = v;
        } else {
          Vb[row * 1024 + (col - 2048)] = v;
        }
      }
    }
  }
}

// ---------------------------------------------------------------------------
// Output GEMM: out(4096,1024) = o @ Wout^T + bout, fp32 out. Same engine.
// ---------------------------------------------------------------------------
__global__ __launch_bounds__(256, 2) void gemm_out(
    const u16* __restrict__ A, const u16* __restrict__ B,
    const float* __restrict__ bias, float* __restrict__ C)
{
  __shared__ u16 As[128 * 32];
  __shared__ u16 Bs[128 * 32];

  const int K = 1024, N = 1024;
  const int tid  = threadIdx.x;
  const int lane = tid & 63;
  const int wave = tid >> 6;
  const int quad = lane >> 4;
  const int c16  = lane & 15;
  const int wr   = wave >> 1;
  const int wc   = wave & 1;
  const long m0 = (long)blockIdx.y * 128;
  const long n0 = (long)blockIdx.x * 128;

  const int srow   = wave * 32 + (lane >> 2);
  const int schunk = (lane & 3) ^ ((lane >> 3) & 3);
  const u16* gA0 = &A[(m0 + srow) * K + schunk * 8];
  const u16* gA1 = &A[(m0 + srow + 16) * K + schunk * 8];
  const u16* gB0 = &B[(n0 + srow) * K + schunk * 8];
  const u16* gB1 = &B[(n0 + srow + 16) * K + schunk * 8];
  u16* const lA0 = &As[(wave * 32) * 32];
  u16* const lA1 = &As[(wave * 32 + 16) * 32];
  u16* const lB0 = &Bs[(wave * 32) * 32];
  u16* const lB1 = &Bs[(wave * 32 + 16) * 32];

  const int cs = (quad ^ ((c16 >> 1) & 3)) * 8;
  const u16* pa[4]; const u16* pb[4];
#pragma unroll
  for (int i = 0; i < 4; ++i) {
    pa[i] = &As[(wr * 64 + i * 16 + c16) * 32 + cs];
    pb[i] = &Bs[(wc * 64 + i * 16 + c16) * 32 + cs];
  }

  f32x4 acc[4][4];
#pragma unroll
  for (int i = 0; i < 4; ++i)
#pragma unroll
    for (int j = 0; j < 4; ++j)
      acc[i][j] = f32x4{0.f, 0.f, 0.f, 0.f};

  for (int k0 = 0; k0 < K; k0 += 32) {
    __syncthreads();
    gll16(gA0, lA0); gll16(gA1, lA1);
    gll16(gB0, lB0); gll16(gB1, lB1);
    gA0 += 32; gA1 += 32; gB0 += 32; gB1 += 32;
    __syncthreads();

    bf16x8 af[4], bfr[4];
#pragma unroll
    for (int i = 0; i < 4; ++i) af[i]  = *(const bf16x8*)pa[i];
#pragma unroll
    for (int j = 0; j < 4; ++j) bfr[j] = *(const bf16x8*)pb[j];
#pragma unroll
    for (int i = 0; i < 4; ++i)
#pragma unroll
      for (int j = 0; j < 4; ++j)
        acc[i][j] = MFMA16(af[i], bfr[j], acc[i][j]);
  }

#pragma unroll
  for (int i = 0; i < 4; ++i) {
    const long row0 = m0 + wr * 64 + i * 16 + quad * 4;
#pragma unroll
    for (int j = 0; j < 4; ++j) {
      const long col = n0 + wc * 64 + j * 16 + c16;
      const float bv = bias[col];
#pragma unroll
      for (int r = 0; r < 4; ++r)
        C[(row0 + r) * N + col] = acc[i][j][r] + bv;
    }
  }
}

// ---------------------------------------------------------------------------
// V repack: Vb(S,D) -> VTp(h, d, key+256) transposed; zeroes pad tiles of
// both Kp and VTp. Grid (72 padded key tiles, 16 heads), 256 threads.
// LDS transpose uses dual-XOR swizzle: element (d, key) stored at
// lds[d*64 + ((key>>3) ^ ((d + (d>>3)) & 7))*8 + (key&7)] -> both the scalar
// transpose writes and the b128 row reads are conflict-free.
// ---------------------------------------------------------------------------
__global__ __launch_bounds__(256, 2) void repack_v(
    const u16* __restrict__ Vb, u16* __restrict__ Kp, u16* __restrict__ VTp)
{
  __shared__ u16 lds[64 * 64];
  const int tile = blockIdx.x;          // padded key tile, 0..71
  const int h    = blockIdx.y;
  const int tid  = threadIdx.x;
  const int kt   = tile * 64 - 256;     // actual key start
  const long vtb = (long)h * 64 * 4608;

  if (kt < 0 || kt >= 4096) {           // pad tile: zero Kp rows + VTp cols
    const int4 z = {0, 0, 0, 0};
    for (int idx = tid; idx < 512; idx += 256) {
      const int r = idx >> 3, c = idx & 7;
      *(int4*)(&Kp[((long)h * 4608 + tile * 64 + r) * 64 + c * 8]) = z;
      *(int4*)(&VTp[vtb + (long)r * 4608 + tile * 64 + c * 8])     = z;
    }
    return;
  }

  for (int idx = tid; idx < 512; idx += 256) {
    const int r = idx >> 3, c = idx & 7;            // key r, d-chunk c
    U8x16 t; t.v = *(const int4*)(&Vb[(long)(kt + r) * 1024 + h * 64 + c * 8]);
#pragma unroll
    for (int j = 0; j < 8; ++j) {
      const int d = c * 8 + j;
      lds[d * 64 + (((r >> 3) ^ ((c + j) & 7)) * 8) + (r & 7)] = t.u[j];
    }
  }
  __syncthreads();
  for (int idx = tid; idx < 512; idx += 256) {
    const int d = idx >> 3, c2 = idx & 7;           // d row, key-chunk c2
    const int sl = (c2 ^ ((d + (d >> 3)) & 7)) * 8;
    const int4 v = *(const int4*)(&lds[d * 64 + sl]);
    *(int4*)(&VTp[vtb + (long)d * 4608 + 256 + kt + c2 * 8]) = v;
  }
}

// ---------------------------------------------------------------------------
// Sliding-window flash attention. Grid (S/128, H), 512 threads = 8 waves.
// Wave w owns queries [qb0+16w, +16). 10 key tiles of 64 cover padded keys
// [qb0, qb0+640) = actual [qb0-256, qb0+384); each wave computes exactly the
// 9 tiles intersecting its band (t in [w>>2, 8+(w>>2)]).
// Staging: 1 gll16/wave/tile/matrix; slot = global chunk ^ (row&7) so all
// fragment reads are conflict-free b128.
// Fixed-max softmax (scores |s|<~8 << 88): p = exp(s/8), no max tracking, no
// rescale; row-sum reduced once at the end. Pad keys (k=0,v=0) give p=1 in
// the denominator, matching the reference's zero-padding exactly.
// P is per-wave in LDS (C-layout -> A-layout), XOR-swizzled, no barrier.
// ---------------------------------------------------------------------------
__global__ __launch_bounds__(512, 4) void swa_fused(
    const u16* __restrict__ Qb, const u16* __restrict__ Kp,
    const u16* __restrict__ VTp, u16* __restrict__ o)
{
  __shared__ u16 Ks[64 * 64];       // (key, d), chunk-swizzled
  __shared__ u16 Vs[64 * 64];       // (d, key), chunk-swizzled
  __shared__ u16 Ps[8 * 16 * 64];   // per-wave (q, key), chunk-swizzled

  const int tid  = threadIdx.x;
  const int lane = tid & 63;
  const int w    = tid >> 6;
  const int quad = lane >> 4;
  const int c16  = lane & 15;
  const int h    = blockIdx.y;
  const int qb0  = blockIdx.x * 128;

  // Q fragments (A-layout), loaded once
  const long qrow = qb0 + w * 16 + c16;
  const bf16x8 aq0 = *(const bf16x8*)(&Qb[qrow * 1024 + h * 64 + quad * 8]);
  const bf16x8 aq1 = *(const bf16x8*)(&Qb[qrow * 1024 + h * 64 + 32 + quad * 8]);

  // staging: wave w stages rows [w*8, w*8+8); lane i -> row w*8+(i>>3),
  // slot i&7, global chunk (i&7)^(i>>3)
  const int srow   = w * 8 + (lane >> 3);
  const int gchunk = (lane & 7) ^ (lane >> 3);
  const u16* gK = &Kp[((long)h * 4608 + qb0 + srow) * 64 + gchunk * 8];
  const u16* gV = &VTp[((long)h * 64 + srow) * 4608 + qb0 + gchunk * 8];
  u16* const lK = &Ks[(w * 8) * 64];
  u16* const lV = &Vs[(w * 8) * 64];

  // fragment pointers (loop-invariant); slot = chunk ^ (row&7), row&7 = c16&7
  const int rsw = c16 & 7;
  const u16* pK[4][2]; const u16* pV[4][2];
#pragma unroll
  for (int t16 = 0; t16 < 4; ++t16) {
    pK[t16][0] = &Ks[(t16 * 16 + c16) * 64 + (quad ^ rsw) * 8];
    pK[t16][1] = &Ks[(t16 * 16 + c16) * 64 + ((4 + quad) ^ rsw) * 8];
    pV[t16][0] = &Vs[(t16 * 16 + c16) * 64 + (quad ^ rsw) * 8];
    pV[t16][1] = &Vs[(t16 * 16 + c16) * 64 + ((4 + quad) ^ rsw) * 8];
  }
  u16* const Pw  = &Ps[w * 1024];
  const u16* pP0 = &Ps[w * 1024 + c16 * 64 + (quad ^ rsw) * 8];
  const u16* pP1 = &Ps[w * 1024 + c16 * 64 + ((4 + quad) ^ rsw) * 8];

  const int t_lo = w >> 2;            // waves 0-3: tiles 0..8; 4-7: 1..9
  const int t_hi = 8 + (w >> 2);
  const int dbase = c16 - 16 * w - quad * 4;  // delta = dbase + t*64 + tcol*16 - r

  f32x4 acc[4];
#pragma unroll
  for (int dt = 0; dt < 4; ++dt) acc[dt] = f32x4{0.f, 0.f, 0.f, 0.f};
  float rsum[4] = {0.f, 0.f, 0.f, 0.f};

  for (int t = 0; t < 10; ++t) {
    __syncthreads();                  // prior tile's K/V reads complete
    gll16(gK, lK); gll16(gV, lV);
    gK += 64 * 64; gV += 64;
    __syncthreads();                  // DMA drained (vmcnt(0) before barrier)
    if (t < t_lo || t > t_hi) continue;

    // S = Q K^T ; mask+exp ; P -> LDS (per-wave, no barrier needed)
#pragma unroll
    for (int tcol = 0; tcol < 4; ++tcol) {
      const bf16x8 bk0 = *(const bf16x8*)pK[tcol][0];
      const bf16x8 bk1 = *(const bf16x8*)pK[tcol][1];
      f32x4 s = f32x4{0.f, 0.f, 0.f, 0.f};
      s = MFMA16(aq0, bk0, s);
      s = MFMA16(aq1, bk1, s);
#pragma unroll
      for (int r = 0; r < 4; ++r) {
        const int delta = dbase + t * 64 + tcol * 16 - r;
        const float p = ((u32)delta < 512u) ? __expf(s[r] * 0.125f) : 0.f;
        rsum[r] += p;
        const int q  = quad * 4 + r;
        const int kc = tcol * 16 + c16;
        Pw[q * 64 + (((kc >> 3) ^ (q & 7)) * 8) + (kc & 7)] = f2b(p);
      }
    }

    // O += P V
    const bf16x8 ap0 = *(const bf16x8*)pP0;
    const bf16x8 ap1 = *(const bf16x8*)pP1;
#pragma unroll
    for (int dt = 0; dt < 4; ++dt) {
      const bf16x8 bv0 = *(const bf16x8*)pV[dt][0];
      const bf16x8 bv1 = *(const bf16x8*)pV[dt][1];
      acc[dt] = MFMA16(ap0, bv0, acc[dt]);
      acc[dt] = MFMA16(ap1, bv1, acc[dt]);
    }
  }

  // row-sum reduction across the 16 lanes holding each C-row (once)
#pragma unroll
  for (int off = 1; off < 16; off <<= 1)
#pragma unroll
    for (int r = 0; r < 4; ++r)
      rsum[r] += __shfl_xor(rsum[r], off, 64);

  const int qp = qb0 + w * 16 + quad * 4;
#pragma unroll
  for (int r = 0; r < 4; ++r) {
    const float inv = 1.f / rsum[r];
#pragma unroll
    for (int dt = 0; dt < 4; ++dt)
      o[(long)(qp + r) * 1024 + h * 64 + dt * 16 + c16] = f2b(acc[dt][r] * inv);
  }
}

// ---------------------------------------------------------------------------
extern "C" void kernel_launch(void* const* d_in, const int* in_sizes, int n_in,
                              void* d_out, int out_size, void* d_ws, size_t ws_size,
                              hipStream_t stream)
{
  const float* x    = (const float*)d_in[0];   // (4096, 1024)
  const float* Wqkv = (const float*)d_in[1];   // (3072, 1024)
  const float* bqkv = (const float*)d_in[2];   // (3072,)
  const float* Wout = (const float*)d_in[3];   // (1024, 1024)
  const float* bout = (const float*)d_in[4];   // (1024,)
  float* out = (float*)d_out;                  // (4096, 1024)

  // ws layout (u16 elements): 52.4 MB total
  u16* xb    = (u16*)d_ws;                         // 4096*1024
  u16* wqkvb = xb    + (size_t)4096 * 1024;        // 3072*1024
  u16* woutb = wqkvb + (size_t)3072 * 1024;        // 1024*1024
  u16* Qb    = woutb + (size_t)1024 * 1024;        // 4096*1024
  u16* Kp    = Qb    + (size_t)4096 * 1024;        // 16*4608*64
  u16* VTp   = Kp    + (size_t)16 * 4608 * 64;     // 16*64*4608
  u16* Vb    = VTp   + (size_t)16 * 4608 * 64;     // 4096*1024 (o aliases)
  u16* o     = Vb;                                 // Vb dead after repack_v

  cvt_f32_bf16<<<4096 * 1024 / 8 / 256, 256, 0, stream>>>(x, xb, 4096 * 1024 / 8);
  cvt_f32_bf16<<<3072 * 1024 / 8 / 256, 256, 0, stream>>>(Wqkv, wqkvb, 3072 * 1024 / 8);
  cvt_f32_bf16<<<1024 * 1024 / 8 / 256, 256, 0, stream>>>(Wout, woutb, 1024 * 1024 / 8);

  gemm_qkv<<<dim3(3072 / 128, 4096 / 128), 256, 0, stream>>>(
      xb, wqkvb, bqkv, Qb, Kp, Vb);
  repack_v<<<dim3(72, 16), 256, 0, stream>>>(Vb, Kp, VTp);
  swa_fused<<<dim3(4096 / 128, 16), 512, 0, stream>>>(Qb, Kp, VTp, o);
  gemm_out<<<dim3(1024 / 128, 4096 / 128), 256, 0, stream>>>(o, woutb, bout, out);
}